// Round 7
// baseline (24.349 us; speedup 1.0000x reference)
//
#include <hip/hip_runtime.h>

#define NUM_CLASSES 6625
#define FEAT_DIM 96
#define NROWS 4096
#define CLAMP_MIN 1e-12
#define CLAMP_MAX 1e12

// clang ext_vector type so __builtin_nontemporal_load works (HIP's float4 is
// a struct, not a vector type).
typedef float vfloat4 __attribute__((ext_vector_type(4)));

// One 256-thread block per row. Each thread issues all 7 of its float4 loads
// up front as NON-TEMPORAL (pure stream, no reuse -> bypass L2 allocation),
// compares into 7 independent chains (within-chain element indices increase
// monotonically, so strict '>' keeps the first occurrence == jnp.argmax),
// then wave shuffle reduce + one LDS merge. Wave 0 computes the fused f64
// squared distance to centers[label]; feats row is prefetched at kernel
// start (address independent of label) so the epilogue only waits on the
// centers gather.
__global__ __launch_bounds__(256) void argmax_dist_kernel(
    const float* __restrict__ pred,
    const float* __restrict__ feats,
    const float* __restrict__ centers,
    double* __restrict__ dists)
{
    const int C = NUM_CLASSES;
    const int row = blockIdx.x;
    const int tid = threadIdx.x;
    const float* p = pred + (size_t)row * C;
    const int lane = tid & 63;

    // Prefetch feats row for the epilogue (wave 0 only uses it, but issuing
    // here hides the load under the argmax phase).
    float f_lo = 0.0f, f_hi = 0.0f;
    if (tid < 64) {
        const float* frow = feats + row * FEAT_DIM;
        f_lo = frow[lane];
        if (lane < 32) f_hi = frow[lane + 64];
    }

    // Row base element offset is row*6625 ≡ row (mod 4): scalar prefix to
    // reach 16B alignment for float4 loads.
    const int prefix = (4 - (row & 3)) & 3;
    const int nvec = (C - prefix) >> 2;              // 1655 or 1656
    const vfloat4* pv = (const vfloat4*)(p + prefix);

    // ---- Issue every load this thread needs, back to back (nt). ----
    vfloat4 v0 = __builtin_nontemporal_load(pv + tid);
    vfloat4 v1 = __builtin_nontemporal_load(pv + tid + 256);
    vfloat4 v2 = __builtin_nontemporal_load(pv + tid + 512);
    vfloat4 v3 = __builtin_nontemporal_load(pv + tid + 768);
    vfloat4 v4 = __builtin_nontemporal_load(pv + tid + 1024);
    vfloat4 v5 = __builtin_nontemporal_load(pv + tid + 1280);
    const int i6 = tid + 1536;
    const bool val6 = i6 < nvec;
    vfloat4 v6 = __builtin_nontemporal_load(pv + (val6 ? i6 : (nvec - 1)));
    // Prefix scalar (element indices 0..prefix-1, the smallest).
    const bool valp = tid < prefix;
    float vp = p[valp ? tid : 0];
    // Tail scalars (largest element indices: tailstart..C-1).
    const int tailstart = prefix + 4 * nvec;
    const bool valt = tid < (C - tailstart);
    float vt = p[valt ? (tailstart + tid) : 0];

    // ---- Compare phase. ----
    float b0, b1, b2, b3, b4, b5, b6;
    int   j0, j1, j2, j3, j4, j5, j6;
    b0=b1=b2=b3=b4=b5=b6 = -__builtin_inff();
    j0=j1=j2=j3=j4=j5=j6 = C;

    // Chain 0 starts with the prefix element (index tid < prefix+4*tid).
    if (valp) { b0 = vp; j0 = tid; }

    #define CHAIN(vv, bb, jj, vecidx) { \
        const int e = prefix + 4 * (vecidx); \
        if (vv.x > bb) { bb = vv.x; jj = e; } \
        if (vv.y > bb) { bb = vv.y; jj = e + 1; } \
        if (vv.z > bb) { bb = vv.z; jj = e + 2; } \
        if (vv.w > bb) { bb = vv.w; jj = e + 3; } }
    CHAIN(v0, b0, j0, tid)
    CHAIN(v1, b1, j1, tid + 256)
    CHAIN(v2, b2, j2, tid + 512)
    CHAIN(v3, b3, j3, tid + 768)
    CHAIN(v4, b4, j4, tid + 1024)
    CHAIN(v5, b5, j5, tid + 1280)
    if (val6) CHAIN(v6, b6, j6, i6)
    #undef CHAIN
    // Tail folds into chain 6: its element indices exceed everything there.
    if (valt) {
        const int e = tailstart + tid;
        if (vt > b6) { b6 = vt; j6 = e; }
    }

    // Merge chains (value desc, index asc on tie).
    float best = b0; int bidx = j0;
    #define MERGE(bb, jj) if (bb > best || (bb == best && jj < bidx)) { best = bb; bidx = jj; }
    MERGE(b1, j1) MERGE(b2, j2) MERGE(b3, j3)
    MERGE(b4, j4) MERGE(b5, j5) MERGE(b6, j6)
    #undef MERGE

    // Wave shuffle reduce (64 lanes), no barrier.
    for (int off = 32; off > 0; off >>= 1) {
        float ov = __shfl_down(best, off, 64);
        int   oi = __shfl_down(bidx, off, 64);
        if (ov > best || (ov == best && oi < bidx)) { best = ov; bidx = oi; }
    }

    // Cross-wave merge: 4 partials through LDS, single barrier.
    __shared__ float swv[4];
    __shared__ int   swi[4];
    const int wave = tid >> 6;
    if (lane == 0) { swv[wave] = best; swi[wave] = bidx; }
    __syncthreads();
    if (tid >= 64) return;

    float bv = swv[0]; int bi = swi[0];
    #pragma unroll
    for (int w = 1; w < 4; ++w) {
        float v2 = swv[w]; int i2 = swi[w];
        if (v2 > bv || (v2 == bv && i2 < bi)) { bv = v2; bi = i2; }
    }
    const int label = bi;  // uniform across wave 0

    // f64 squared distance: lane handles element lane (+ lane+64 if lane<32).
    const float* crow = centers + (size_t)label * FEAT_DIM;
    double d0 = (double)f_lo - (double)crow[lane];
    double acc = d0 * d0;
    if (lane < 32) {
        double d1 = (double)f_hi - (double)crow[lane + 64];
        acc += d1 * d1;
    }
    for (int off = 32; off > 0; off >>= 1)
        acc += __shfl_down(acc, off, 64);
    if (lane == 0) {
        double dn = acc;
        dn = dn < CLAMP_MIN ? CLAMP_MIN : (dn > CLAMP_MAX ? CLAMP_MAX : dn);
        dists[row] = dn;
    }
}

// 256-thread final reduction: each thread makes 8 coalesced double2 loads
// (one latency round), wave shuffle reduce, LDS merge of 4 wave partials.
// Adds the (C-1)*1e-12 constant from the reference's clip-after-mask on the
// zeroed columns.
__global__ __launch_bounds__(256) void reduce_kernel(
    const double* __restrict__ dists, float* __restrict__ out)
{
    const int tid = threadIdx.x;
    const double2* d2 = (const double2*)dists;      // 2048 double2
    double2 a0 = d2[tid];
    double2 a1 = d2[tid + 256];
    double2 a2 = d2[tid + 512];
    double2 a3 = d2[tid + 768];
    double2 a4 = d2[tid + 1024];
    double2 a5 = d2[tid + 1280];
    double2 a6 = d2[tid + 1536];
    double2 a7 = d2[tid + 1792];
    double s = ((a0.x + a0.y) + (a1.x + a1.y))
             + ((a2.x + a2.y) + (a3.x + a3.y))
             + ((a4.x + a4.y) + (a5.x + a5.y))
             + ((a6.x + a6.y) + (a7.x + a7.y));
    for (int off = 32; off > 0; off >>= 1)
        s += __shfl_down(s, off, 64);
    __shared__ double sw[4];
    const int wave = tid >> 6;
    const int lane = tid & 63;
    if (lane == 0) sw[wave] = s;
    __syncthreads();
    if (tid == 0) {
        double t = (sw[0] + sw[1]) + (sw[2] + sw[3]);
        out[0] = (float)(t / (double)NROWS
                         + (double)(NUM_CLASSES - 1) * CLAMP_MIN);
    }
}

extern "C" void kernel_launch(void* const* d_in, const int* in_sizes, int n_in,
                              void* d_out, int out_size, void* d_ws, size_t ws_size,
                              hipStream_t stream) {
    const float* feats   = (const float*)d_in[0];  // [4096, 96]
    const float* pred    = (const float*)d_in[1];  // [4096, 6625]
    const float* centers = (const float*)d_in[2];  // [6625, 96]
    double* dists = (double*)d_ws;                 // 4096 * 8 B = 32 KiB
    float* out = (float*)d_out;

    argmax_dist_kernel<<<NROWS, 256, 0, stream>>>(pred, feats, centers, dists);
    reduce_kernel<<<1, 256, 0, stream>>>(dists, out);
}

// Round 8
// 24.162 us; speedup vs baseline: 1.0077x; 1.0077x over previous
//
#include <hip/hip_runtime.h>

#define NUM_CLASSES 6625
#define FEAT_DIM 96
#define NROWS 4096
#define CLAMP_MIN 1e-12
#define CLAMP_MAX 1e12

// clang ext_vector type so __builtin_nontemporal_load works (HIP's float4 is
// a struct, not a vector type).
typedef float vfloat4 __attribute__((ext_vector_type(4)));

// One 256-thread block per row (R6 structure, best measured: 23.77us).
// Each thread issues its 6 unconditional float4 loads up front as
// NON-TEMPORAL (pure stream, no reuse -> bypass L2 allocation); the 7th
// vector load and the prefix/tail scalar loads are branch-gated so waves
// with no valid work skip the VMEM issue entirely (s_cbranch_execz).
// 7 independent compare chains (within-chain element indices increase
// monotonically, so strict '>' keeps the first occurrence == jnp.argmax),
// wave shuffle reduce, one LDS merge, then wave 0 computes the fused f64
// squared distance to centers[label].
__global__ __launch_bounds__(256) void argmax_dist_kernel(
    const float* __restrict__ pred,
    const float* __restrict__ feats,
    const float* __restrict__ centers,
    double* __restrict__ dists)
{
    const int C = NUM_CLASSES;
    const int row = blockIdx.x;
    const int tid = threadIdx.x;
    const float* p = pred + (size_t)row * C;

    // Row base element offset is row*6625 ≡ row (mod 4): scalar prefix to
    // reach 16B alignment for float4 loads.
    const int prefix = (4 - (row & 3)) & 3;
    const int nvec = (C - prefix) >> 2;              // 1655 or 1656
    const vfloat4* pv = (const vfloat4*)(p + prefix);

    // ---- Unconditional loads, back to back (nt). ----
    vfloat4 v0 = __builtin_nontemporal_load(pv + tid);
    vfloat4 v1 = __builtin_nontemporal_load(pv + tid + 256);
    vfloat4 v2 = __builtin_nontemporal_load(pv + tid + 512);
    vfloat4 v3 = __builtin_nontemporal_load(pv + tid + 768);
    vfloat4 v4 = __builtin_nontemporal_load(pv + tid + 1024);
    vfloat4 v5 = __builtin_nontemporal_load(pv + tid + 1280);
    // 7th vector load, branch-gated: only tids < nvec-1536 (~120) need it;
    // waves 2..3 skip the instruction entirely.
    const int i6 = tid + 1536;
    const bool val6 = i6 < nvec;
    vfloat4 v6 = {};
    if (val6) v6 = __builtin_nontemporal_load(pv + i6);

    // ---- Compare phase. ----
    float b0, b1, b2, b3, b4, b5, b6;
    int   j0, j1, j2, j3, j4, j5, j6;
    b0=b1=b2=b3=b4=b5=b6 = -__builtin_inff();
    j0=j1=j2=j3=j4=j5=j6 = C;

    // Prefix scalars (element indices 0..prefix-1, smaller than anything
    // chain 0 sees later): at most 3 lanes of wave 0 load.
    if (tid < prefix) { b0 = p[tid]; j0 = tid; }

    #define CHAIN(vv, bb, jj, vecidx) { \
        const int e = prefix + 4 * (vecidx); \
        if (vv.x > bb) { bb = vv.x; jj = e; } \
        if (vv.y > bb) { bb = vv.y; jj = e + 1; } \
        if (vv.z > bb) { bb = vv.z; jj = e + 2; } \
        if (vv.w > bb) { bb = vv.w; jj = e + 3; } }
    CHAIN(v0, b0, j0, tid)
    CHAIN(v1, b1, j1, tid + 256)
    CHAIN(v2, b2, j2, tid + 512)
    CHAIN(v3, b3, j3, tid + 768)
    CHAIN(v4, b4, j4, tid + 1024)
    CHAIN(v5, b5, j5, tid + 1280)
    if (val6) CHAIN(v6, b6, j6, i6)
    #undef CHAIN

    // Scalar tail (largest element indices), branch-gated: folds into chain
    // 6 whose prior indices are all smaller.
    {
        const int tailstart = prefix + 4 * nvec;
        if (tid < C - tailstart) {
            const int e = tailstart + tid;
            const float vt = p[e];
            if (vt > b6) { b6 = vt; j6 = e; }
        }
    }

    // Merge chains (value desc, index asc on tie).
    float best = b0; int bidx = j0;
    #define MERGE(bb, jj) if (bb > best || (bb == best && jj < bidx)) { best = bb; bidx = jj; }
    MERGE(b1, j1) MERGE(b2, j2) MERGE(b3, j3)
    MERGE(b4, j4) MERGE(b5, j5) MERGE(b6, j6)
    #undef MERGE

    // Wave shuffle reduce (64 lanes), no barrier.
    for (int off = 32; off > 0; off >>= 1) {
        float ov = __shfl_down(best, off, 64);
        int   oi = __shfl_down(bidx, off, 64);
        if (ov > best || (ov == best && oi < bidx)) { best = ov; bidx = oi; }
    }

    // Cross-wave merge: 4 partials through LDS, single barrier.
    __shared__ float swv[4];
    __shared__ int   swi[4];
    const int wave = tid >> 6;
    const int lane = tid & 63;
    if (lane == 0) { swv[wave] = best; swi[wave] = bidx; }
    __syncthreads();
    if (tid >= 64) return;

    float bv = swv[0]; int bi = swi[0];
    #pragma unroll
    for (int w = 1; w < 4; ++w) {
        float v2 = swv[w]; int i2 = swi[w];
        if (v2 > bv || (v2 == bv && i2 < bi)) { bv = v2; bi = i2; }
    }
    const int label = bi;  // uniform across wave 0

    // f64 squared distance: lane handles element lane (+ lane+64 if lane<32).
    const float* frow = feats + row * FEAT_DIM;
    const float* crow = centers + (size_t)label * FEAT_DIM;
    double d0 = (double)frow[lane] - (double)crow[lane];
    double acc = d0 * d0;
    if (lane < 32) {
        double d1 = (double)frow[lane + 64] - (double)crow[lane + 64];
        acc += d1 * d1;
    }
    for (int off = 32; off > 0; off >>= 1)
        acc += __shfl_down(acc, off, 64);
    if (lane == 0) {
        double dn = acc;
        dn = dn < CLAMP_MIN ? CLAMP_MIN : (dn > CLAMP_MAX ? CLAMP_MAX : dn);
        dists[row] = dn;
    }
}

// Single-WAVE final reduction (R6 version, best measured): 64 lanes, 4
// independent accumulation chains, shuffle-only (no LDS, no barriers). Adds
// the (C-1)*1e-12 constant from the reference's clip-after-mask on the
// zeroed columns.
__global__ __launch_bounds__(64) void reduce_kernel(
    const double* __restrict__ dists, float* __restrict__ out)
{
    const int lane = threadIdx.x;
    double s0 = 0.0, s1 = 0.0, s2 = 0.0, s3 = 0.0;
    #pragma unroll
    for (int k = 0; k < 16; ++k) {
        s0 += dists[lane + 64 * (4 * k + 0)];
        s1 += dists[lane + 64 * (4 * k + 1)];
        s2 += dists[lane + 64 * (4 * k + 2)];
        s3 += dists[lane + 64 * (4 * k + 3)];
    }
    double s = (s0 + s1) + (s2 + s3);
    for (int off = 32; off > 0; off >>= 1)
        s += __shfl_down(s, off, 64);
    if (lane == 0)
        out[0] = (float)(s / (double)NROWS
                         + (double)(NUM_CLASSES - 1) * CLAMP_MIN);
}

extern "C" void kernel_launch(void* const* d_in, const int* in_sizes, int n_in,
                              void* d_out, int out_size, void* d_ws, size_t ws_size,
                              hipStream_t stream) {
    const float* feats   = (const float*)d_in[0];  // [4096, 96]
    const float* pred    = (const float*)d_in[1];  // [4096, 6625]
    const float* centers = (const float*)d_in[2];  // [6625, 96]
    double* dists = (double*)d_ws;                 // 4096 * 8 B = 32 KiB
    float* out = (float*)d_out;

    argmax_dist_kernel<<<NROWS, 256, 0, stream>>>(pred, feats, centers, dists);
    reduce_kernel<<<1, 64, 0, stream>>>(dists, out);
}